// Round 5
// baseline (364.861 us; speedup 1.0000x reference)
//
#include <hip/hip_runtime.h>

// Fused DigitConvolutionalModel, R5:
//   conv3x3(valid) 28x28 -> 676 -> fc1(100)+ReLU (bf16 MFMA 16x16x32) -> fc2(10)
// R1-R4 invariant bottleneck: conv's global loads put consecutive lanes 112 B
// apart -> 64 distinct cache lines per load instr (4x line amplification,
// TA/L1 address-path serialization ~30-55 us/CU). Fix: Phase 0 stages x
// PERFECTLY COALESCED into LDS as bf16; conv reads LDS instead of global.
// BM=16 images/block, 256 thr. LDS: xbuf 25.2 KB + cbuf 22.8 KB = 48 KB
// -> 3 blocks/CU. B-fragments pre-swizzled bf16 (bias folded at k=676).

typedef short  s16x8 __attribute__((ext_vector_type(8)));   // 8 bf16
typedef float  f32x4 __attribute__((ext_vector_type(4)));   // 16x16 acc

#define BM   16     // images per block
#define XSTR 788    // xbuf image stride (ushorts): 1576 B, 8B-aligned rows
#define CSTR 712    // cbuf row stride (bf16): 1424 B
#define HSTR 132    // hbuf row stride (floats)
#define NT   8      // n-tiles of 16 (N=100 -> 7 live + 1 zero)
#define KC   22     // k-chunks of 32 (K=676 -> pad 704, bias row at k=676)

__device__ __forceinline__ unsigned short f2bf(float f) {
    unsigned int u = __builtin_bit_cast(unsigned int, f);
    u = (u + 0x7fffu + ((u >> 16) & 1u)) >> 16;
    return (unsigned short)u;
}
__device__ __forceinline__ float bflo(unsigned int u) {   // low bf16 -> f32
    return __builtin_bit_cast(float, u << 16);
}
__device__ __forceinline__ float bfhi(unsigned int u) {   // high bf16 -> f32
    return __builtin_bit_cast(float, u & 0xffff0000u);
}

// ---- prep: W1 [100][676] fp32 -> bw [t][kc][lane][8] bf16 (B-fragment) ----
// lane (n=lane&15, q=lane>>4) holds B[k = kc*32 + q*8 + j][n = t*16 + (lane&15)]
// k==676 -> b1[n] (bias row); n>=100 or k>676 -> 0.
extern "C" __global__ void __launch_bounds__(256)
prep_w1(const float* __restrict__ W1, const float* __restrict__ b1,
        unsigned short* __restrict__ bw)
{
    int id = blockIdx.x * 256 + threadIdx.x;
    if (id >= NT * KC * 64) return;
    int lane = id & 63;
    int kc   = (id >> 6) % KC;
    int t    = id / (KC * 64);
    int n    = t * 16 + (lane & 15);
    int k0   = kc * 32 + (lane >> 4) * 8;
    unsigned short v[8];
#pragma unroll
    for (int j = 0; j < 8; ++j) {
        int k = k0 + j;
        float f = 0.f;
        if (n < 100) {
            if (k < 676)       f = W1[(size_t)n * 676 + k];
            else if (k == 676) f = b1[n];
        }
        v[j] = f2bf(f);
    }
    *(uint4*)(bw + (size_t)id * 8) = *(const uint4*)v;
}

// ---------------------------- main kernel ----------------------------------
extern "C" __global__ void __launch_bounds__(256, 4)
digit_model_fused(const float* __restrict__ x,
                  const float* __restrict__ cw9,
                  const unsigned short* __restrict__ bw,
                  const float* __restrict__ W2,
                  const float* __restrict__ b2,
                  float* __restrict__ out)
{
    __shared__ __align__(16) unsigned char smem[BM * XSTR * 2 + BM * CSTR * 2]; // 48000 B
    unsigned short* xbuf = (unsigned short*)smem;                  // [16][788] bf16 x
    unsigned short* cbuf = (unsigned short*)(smem + BM * XSTR * 2);// [16][712] bf16 conv
    float*          hbuf = (float*)smem;                           // phase 3 (aliases xbuf)

    const int tid  = threadIdx.x;
    const int lane = tid & 63;
    const int wv   = tid >> 6;       // 0..3
    const int q    = lane >> 4;      // k-quarter
    const int mn   = lane & 15;      // m row / n col within tile
    const int m0   = blockIdx.x * BM;

    float cw[9];
#pragma unroll
    for (int i = 0; i < 9; ++i) cw[i] = cw9[i];

    // K-pad [676,712): zeros except A[mi][676] = 1.0 (bias multiplicand)
    for (int p = tid; p < BM * 18; p += 256) {
        int mi = p / 18, qq = p - mi * 18;
        *(unsigned int*)(cbuf + mi * CSTR + 676 + qq * 2) = (qq == 0) ? 0x3F80u : 0u;
    }

    // -------- Phase 0: stage x -> bf16 xbuf, PERFECTLY COALESCED ------------
    // Block's 16 images are contiguous: 16*784 floats = 3136 float4s.
    {
        const float4* xg = (const float4*)(x + (size_t)m0 * 784);
        for (int p = tid; p < BM * 196; p += 256) {
            int mi = p / 196, g = p - mi * 196;
            float4 v = xg[p];                       // lanes: consecutive 16 B
            unsigned int lo = (unsigned int)f2bf(v.x) | ((unsigned int)f2bf(v.y) << 16);
            unsigned int hi = (unsigned int)f2bf(v.z) | ((unsigned int)f2bf(v.w) << 16);
            uint2 w; w.x = lo; w.y = hi;
            *(uint2*)(xbuf + mi * XSTR + g * 4) = w;   // 8B-aligned
        }
    }
    __syncthreads();

    // -------- Phase 1: conv fp32 from LDS (compile-time indexing only) ------
    for (int task = tid; task < BM * 26; task += 256) {
        int mi = task / 26, r = task - mi * 26;
        const unsigned short* irow = xbuf + mi * XSTR + r * 28;
        float acc[26];
#pragma unroll
        for (int c = 0; c < 26; ++c) acc[c] = 0.f;
#pragma unroll
        for (int dr = 0; dr < 3; ++dr) {
            float rowv[28];
            const uint2* rp = (const uint2*)(irow + dr * 28);   // 8B-aligned
#pragma unroll
            for (int g = 0; g < 7; ++g) {
                uint2 u = rp[g];                                // ds_read_b64
                rowv[g*4+0] = bflo(u.x); rowv[g*4+1] = bfhi(u.x);
                rowv[g*4+2] = bflo(u.y); rowv[g*4+3] = bfhi(u.y);
            }
#pragma unroll
            for (int dc = 0; dc < 3; ++dc) {
                float w = cw[dr*3+dc];
#pragma unroll
                for (int c = 0; c < 26; ++c)
                    acc[c] = fmaf(rowv[c + dc], w, acc[c]);
            }
        }
        unsigned short* dst = cbuf + mi * CSTR + r * 26;        // 4B-aligned
#pragma unroll
        for (int c = 0; c < 26; c += 2)
            *(unsigned int*)(dst + c) =
                (unsigned int)f2bf(acc[c]) | ((unsigned int)f2bf(acc[c+1]) << 16);
    }
    __syncthreads();

    // -------- Phase 2: MFMA 16x16x32, 2 n-tiles per wave --------------------
    // A: lane holds A[m=mn][k=q*8+j]; B: lane holds B[k=q*8+j][n=mn]
    f32x4 acc0, acc1;
#pragma unroll
    for (int i = 0; i < 4; ++i) { acc0[i] = 0.f; acc1[i] = 0.f; }

    const unsigned short* arow = cbuf + mn * CSTR + q * 8;
    const uint4* bwv = (const uint4*)bw;
    const int t0 = wv, t1 = wv + 4;

    uint4 a  = *(const uint4*)(arow);                 // ds_read_b128
    uint4 b0 = bwv[(t0 * KC) * 64 + lane];            // coalesced 1 KB/wave
    uint4 b1 = bwv[(t1 * KC) * 64 + lane];
    for (int kc = 0; kc < KC; ++kc) {
        int kn = (kc + 1 < KC) ? kc + 1 : kc;         // clamped 1-deep prefetch
        uint4 na  = *(const uint4*)(arow + kn * 32);
        uint4 nb0 = bwv[(t0 * KC + kn) * 64 + lane];
        uint4 nb1 = bwv[(t1 * KC + kn) * 64 + lane];
        acc0 = __builtin_amdgcn_mfma_f32_16x16x32_bf16(
                   __builtin_bit_cast(s16x8, a), __builtin_bit_cast(s16x8, b0),
                   acc0, 0, 0, 0);
        acc1 = __builtin_amdgcn_mfma_f32_16x16x32_bf16(
                   __builtin_bit_cast(s16x8, a), __builtin_bit_cast(s16x8, b1),
                   acc1, 0, 0, 0);
        a = na; b0 = nb0; b1 = nb1;
    }
    __syncthreads();          // cbuf reads drained; smem front reusable as hbuf

    // -------- Phase 3a: ReLU (bias already folded) -> hbuf ------------------
    // C/D: row(image) = q*4 + r, col(neuron) = mn  (verified mapping)
#pragma unroll
    for (int r = 0; r < 4; ++r) {
        int row = q * 4 + r;
        float v0 = acc0[r]; v0 = v0 > 0.f ? v0 : 0.f;
        float v1 = acc1[r]; v1 = v1 > 0.f ? v1 : 0.f;
        hbuf[row * HSTR + t0 * 16 + mn] = v0;   // cols >=100 are 0, never read
        hbuf[row * HSTR + t1 * 16 + mn] = v1;
    }
    __syncthreads();

    // -------- Phase 3b: fc2 (fp32 VALU) + store -----------------------------
    for (int p = tid; p < BM * 10; p += 256) {
        int mi = p / 10, o = p - mi * 10;
        const float4* hv = (const float4*)(hbuf + mi * HSTR);
        const float4* w2 = (const float4*)(W2 + (size_t)o * 100);
        float s = b2[o];
#pragma unroll
        for (int g = 0; g < 25; ++g) {
            float4 h4 = hv[g], w4 = w2[g];
            s += h4.x*w4.x + h4.y*w4.y + h4.z*w4.z + h4.w*w4.w;
        }
        out[(size_t)(m0 + mi) * 10 + o] = s;
    }
}

extern "C" void kernel_launch(void* const* d_in, const int* in_sizes, int n_in,
                              void* d_out, int out_size, void* d_ws, size_t ws_size,
                              hipStream_t stream) {
    const float* x  = (const float*)d_in[0];
    const float* cw = (const float*)d_in[1];
    const float* W1 = (const float*)d_in[2];
    const float* b1 = (const float*)d_in[3];
    const float* W2 = (const float*)d_in[4];
    const float* b2 = (const float*)d_in[5];
    float* out = (float*)d_out;
    unsigned short* bw = (unsigned short*)d_ws;    // 180,224 B used

    const int B = in_sizes[0] / 784;               // 65536

    hipLaunchKernelGGL(prep_w1, dim3((NT * KC * 64 + 255) / 256), dim3(256),
                       0, stream, W1, b1, bw);
    hipLaunchKernelGGL(digit_model_fused, dim3(B / BM), dim3(256), 0, stream,
                       x, cw, bw, W2, b2, out);
}

// Round 6
// 321.673 us; speedup vs baseline: 1.1343x; 1.1343x over previous
//
#include <hip/hip_runtime.h>

// DigitConvolutionalModel R6 — conv+fc1 are both linear with no nonlinearity
// between them, so they COMPOSE into one 784->100 linear map W1eff:
//   out = relu(x @ W1eff^T + b1) @ W2^T + b2
// prep_w1eff folds conv weights into W1 (plus bias row at k=784) and emits
// bf16 MFMA B-fragments. Main kernel is a pure streaming GEMM:
//   Phase 0: burst-load x (24 independent coalesced float4/thread -> high MLP,
//            the R1-R5 bottleneck was ~2-3 outstanding loads/wave = 870 GB/s
//            latency-bound ceiling), convert bf16, store padded LDS xbuf.
//   Phase 1: MFMA 16x16x32 bf16, 2 m-tiles x 2 n-tiles per wave, KC=25.
//   Phase 2: ReLU -> hbuf -> fc2 fp32 -> out.
// BM=32 images/block, 256 thr, LDS 51.7 KB -> 3 blocks/CU.

typedef short  s16x8 __attribute__((ext_vector_type(8)));   // 8 bf16
typedef float  f32x4 __attribute__((ext_vector_type(4)));   // 16x16 acc

#define BM   32     // images per block
#define XP   808    // xbuf row stride (bf16 elems): 1616 B, 16B-aligned rows
#define HSTR 132    // hbuf row stride (floats)
#define NT   8      // n-tiles of 16 (N=100 -> 7 live + 1 zero)
#define KC   25     // k-chunks of 32: k<784 data, k==784 bias, k<800 zero

__device__ __forceinline__ unsigned short f2bf_rtne(float f) {
    unsigned int u = __builtin_bit_cast(unsigned int, f);
    u = (u + 0x7fffu + ((u >> 16) & 1u)) >> 16;
    return (unsigned short)u;
}

// ---- prep: W1eff = conv âŠ— fc1 fold -> bf16 B-fragments + bias row --------
// bw[t][kc][lane][8]; lane(n=lane&15, q=lane>>4) holds
//   B[k = kc*32 + q*8 + j][n = t*16 + (lane&15)]
extern "C" __global__ void __launch_bounds__(256)
prep_w1eff(const float* __restrict__ W1, const float* __restrict__ cw9,
           const float* __restrict__ b1, unsigned short* __restrict__ bw)
{
    int id = blockIdx.x * 256 + threadIdx.x;
    if (id >= NT * KC * 64) return;
    int lane = id & 63;
    int kc   = (id >> 6) % KC;
    int t    = id / (KC * 64);
    int n    = t * 16 + (lane & 15);
    int k0   = kc * 32 + (lane >> 4) * 8;

    float cw[9];
#pragma unroll
    for (int i = 0; i < 9; ++i) cw[i] = cw9[i];

    unsigned short v[8];
#pragma unroll
    for (int j = 0; j < 8; ++j) {
        int k = k0 + j;
        float f = 0.f;
        if (n < 100) {
            if (k < 784) {
                int i = k / 28, jj = k % 28;
                for (int dr = 0; dr < 3; ++dr)
                    for (int dc = 0; dc < 3; ++dc) {
                        int a = i - dr, b = jj - dc;
                        if (a >= 0 && a < 26 && b >= 0 && b < 26)
                            f = fmaf(W1[(size_t)n * 676 + a * 26 + b],
                                     cw[dr * 3 + dc], f);
                    }
            } else if (k == 784) {
                f = b1[n];            // bias row; A supplies 1.0 at k=784
            }                         // 785..799: zero
        }
        v[j] = f2bf_rtne(f);
    }
    *(uint4*)(bw + (size_t)id * 8) = *(const uint4*)v;
}

// ---------------------------- main kernel ----------------------------------
extern "C" __global__ void __launch_bounds__(256, 3)
digit_gemm(const float* __restrict__ x,
           const unsigned short* __restrict__ bw,
           const float* __restrict__ W2,
           const float* __restrict__ b2,
           float* __restrict__ out)
{
    __shared__ __align__(16) unsigned char smem[BM * XP * 2];  // 51712 B
    unsigned short* xbuf = (unsigned short*)smem;   // [32][808] bf16 (K-major)
    float*          hbuf = (float*)smem;            // epilogue alias

    const int tid  = threadIdx.x;
    const int lane = tid & 63;
    const int wv   = tid >> 6;       // 0..3
    const int q    = lane >> 4;      // k-quarter
    const int mn   = lane & 15;      // m row / n col within tile
    const int m0   = blockIdx.x * BM;

    // -------- Phase 0a: K-pad [784,800): bias-1.0 at 784, zeros after -------
    {   // 32 rows x 8 uints = 256 tasks, exactly one per thread
        int mi = tid >> 3, u = tid & 7;
        *(unsigned int*)(xbuf + mi * XP + 784 + u * 2) = (u == 0) ? 0x3F80u : 0u;
    }

    // -------- Phase 0b: burst-load x (high MLP), convert bf16, -> xbuf ------
    // 32*784 floats = 6272 float4; thread handles g = tid + 256*i, bursts of 8
    const float4* xg = (const float4*)(x + (size_t)m0 * 784);
    for (int rr = 0; rr < 3; ++rr) {
        float4 v[8];
#pragma unroll
        for (int i = 0; i < 8; ++i)
            v[i] = xg[tid + 256 * (rr * 8 + i)];       // 8 independent loads
#pragma unroll
        for (int i = 0; i < 8; ++i) {
            int g  = tid + 256 * (rr * 8 + i);
            int mi = g / 196, c4 = g - mi * 196;       // 196 float4 per image
            unsigned int ax = __builtin_bit_cast(unsigned int, v[i].x) + 0x8000u;
            unsigned int ay = __builtin_bit_cast(unsigned int, v[i].y) + 0x8000u;
            unsigned int az = __builtin_bit_cast(unsigned int, v[i].z) + 0x8000u;
            unsigned int aw = __builtin_bit_cast(unsigned int, v[i].w) + 0x8000u;
            uint2 w;
            w.x = (ax >> 16) | (ay & 0xffff0000u);
            w.y = (az >> 16) | (aw & 0xffff0000u);
            *(uint2*)(xbuf + mi * XP + c4 * 4) = w;    // 8B-aligned
        }
    }
    if (tid < 128) {                                    // tail: g = 6144+tid
        int g  = 6144 + tid;
        float4 vv = xg[g];
        int mi = g / 196, c4 = g - mi * 196;
        unsigned int ax = __builtin_bit_cast(unsigned int, vv.x) + 0x8000u;
        unsigned int ay = __builtin_bit_cast(unsigned int, vv.y) + 0x8000u;
        unsigned int az = __builtin_bit_cast(unsigned int, vv.z) + 0x8000u;
        unsigned int aw = __builtin_bit_cast(unsigned int, vv.w) + 0x8000u;
        uint2 w;
        w.x = (ax >> 16) | (ay & 0xffff0000u);
        w.y = (az >> 16) | (aw & 0xffff0000u);
        *(uint2*)(xbuf + mi * XP + c4 * 4) = w;
    }
    __syncthreads();

    // -------- Phase 1: MFMA 16x16x32, 2 m-tiles x 2 n-tiles per wave --------
    // A: lane holds A[m=mn][k=q*8+j]; B: lane holds B[k=q*8+j][n=mn]
    f32x4 acc00, acc01, acc10, acc11;
#pragma unroll
    for (int i = 0; i < 4; ++i) { acc00[i]=0.f; acc01[i]=0.f; acc10[i]=0.f; acc11[i]=0.f; }

    const unsigned short* arow0 = xbuf + mn * XP + q * 8;          // images 0-15
    const unsigned short* arow1 = xbuf + (16 + mn) * XP + q * 8;   // images 16-31
    const uint4* bwv = (const uint4*)bw;
    const int t0 = wv, t1 = wv + 4;

    uint4 a0 = *(const uint4*)(arow0);                // ds_read_b128
    uint4 a1 = *(const uint4*)(arow1);
    uint4 b0 = bwv[(t0 * KC) * 64 + lane];            // coalesced 1 KB/wave
    uint4 b1 = bwv[(t1 * KC) * 64 + lane];
    for (int kc = 0; kc < KC; ++kc) {
        int kn = (kc + 1 < KC) ? kc + 1 : kc;         // clamped 1-deep prefetch
        uint4 na0 = *(const uint4*)(arow0 + kn * 32);
        uint4 na1 = *(const uint4*)(arow1 + kn * 32);
        uint4 nb0 = bwv[(t0 * KC + kn) * 64 + lane];
        uint4 nb1 = bwv[(t1 * KC + kn) * 64 + lane];
        s16x8 av0 = __builtin_bit_cast(s16x8, a0), av1 = __builtin_bit_cast(s16x8, a1);
        s16x8 bv0 = __builtin_bit_cast(s16x8, b0), bv1 = __builtin_bit_cast(s16x8, b1);
        acc00 = __builtin_amdgcn_mfma_f32_16x16x32_bf16(av0, bv0, acc00, 0, 0, 0);
        acc01 = __builtin_amdgcn_mfma_f32_16x16x32_bf16(av0, bv1, acc01, 0, 0, 0);
        acc10 = __builtin_amdgcn_mfma_f32_16x16x32_bf16(av1, bv0, acc10, 0, 0, 0);
        acc11 = __builtin_amdgcn_mfma_f32_16x16x32_bf16(av1, bv1, acc11, 0, 0, 0);
        a0 = na0; a1 = na1; b0 = nb0; b1 = nb1;
    }
    __syncthreads();          // xbuf reads drained; smem reusable as hbuf

    // -------- Phase 2a: ReLU (bias folded in GEMM) -> hbuf ------------------
    // C/D: row(image) = q*4 + r, col(neuron) = mn  (verified mapping)
#pragma unroll
    for (int r = 0; r < 4; ++r) {
        int row = q * 4 + r;
        float v;
        v = acc00[r]; v = v > 0.f ? v : 0.f; hbuf[ row       * HSTR + t0 * 16 + mn] = v;
        v = acc01[r]; v = v > 0.f ? v : 0.f; hbuf[ row       * HSTR + t1 * 16 + mn] = v;
        v = acc10[r]; v = v > 0.f ? v : 0.f; hbuf[(row + 16) * HSTR + t0 * 16 + mn] = v;
        v = acc11[r]; v = v > 0.f ? v : 0.f; hbuf[(row + 16) * HSTR + t1 * 16 + mn] = v;
    }
    __syncthreads();

    // -------- Phase 2b: fc2 (fp32 VALU) + store -----------------------------
    for (int p = tid; p < BM * 10; p += 256) {
        int mi = p / 10, o = p - mi * 10;
        const float4* hv = (const float4*)(hbuf + mi * HSTR);
        const float4* w2 = (const float4*)(W2 + (size_t)o * 100);
        float s = b2[o];
#pragma unroll
        for (int g = 0; g < 25; ++g) {
            float4 h4 = hv[g], w4 = w2[g];
            s += h4.x*w4.x + h4.y*w4.y + h4.z*w4.z + h4.w*w4.w;
        }
        out[(size_t)(m0 + mi) * 10 + o] = s;
    }
}

extern "C" void kernel_launch(void* const* d_in, const int* in_sizes, int n_in,
                              void* d_out, int out_size, void* d_ws, size_t ws_size,
                              hipStream_t stream) {
    const float* x  = (const float*)d_in[0];
    const float* cw = (const float*)d_in[1];
    const float* W1 = (const float*)d_in[2];
    const float* b1 = (const float*)d_in[3];
    const float* W2 = (const float*)d_in[4];
    const float* b2 = (const float*)d_in[5];
    float* out = (float*)d_out;
    unsigned short* bw = (unsigned short*)d_ws;    // NT*KC*64*8*2 = 204,800 B

    const int B = in_sizes[0] / 784;               // 65536

    hipLaunchKernelGGL(prep_w1eff, dim3((NT * KC * 64 + 255) / 256), dim3(256),
                       0, stream, W1, cw, b1, bw);
    hipLaunchKernelGGL(digit_gemm, dim3(B / BM), dim3(256), 0, stream,
                       x, bw, W2, b2, out);
}